// Round 3
// baseline (883.465 us; speedup 1.0000x reference)
//
#include <hip/hip_runtime.h>
#include <cstdint>
#include <type_traits>

typedef unsigned short u16;
typedef __attribute__((ext_vector_type(8))) short short8;
typedef __attribute__((ext_vector_type(4))) float f32x4;

__device__ __forceinline__ u16 f2bf(float f) {
  unsigned x;
  __builtin_memcpy(&x, &f, 4);
  x = x + 0x7fffu + ((x >> 16) & 1u);  // RNE
  return (u16)(x >> 16);
}
__device__ __forceinline__ f32x4 mfma16(short8 a, short8 b, f32x4 c) {
  return __builtin_amdgcn_mfma_f32_16x16x32_bf16(a, b, c, 0, 0, 0);
}
__device__ __forceinline__ void async_cp16(const u16* g, const u16* l) {
  __builtin_amdgcn_global_load_lds(
      (const __attribute__((address_space(1))) unsigned int*)(uintptr_t)g,
      (__attribute__((address_space(3))) unsigned int*)(uintptr_t)l, 16, 0, 0);
}

// ---------------------------------------------------------------------------
// fp32 -> bf16 conversion (vectorized: float4 in, ushort4 out)
// ---------------------------------------------------------------------------
__global__ __launch_bounds__(256)
void cvt_f32_bf16(const float* __restrict__ s, u16* __restrict__ d, long n4) {
  long i = (long)blockIdx.x * 256 + threadIdx.x;
  if (i < n4) {
    float4 f = ((const float4*)s)[i];
    ushort4 o;
    o.x = f2bf(f.x);
    o.y = f2bf(f.y);
    o.z = f2bf(f.z);
    o.w = f2bf(f.w);
    ((ushort4*)d)[i] = o;
  }
}

// ---------------------------------------------------------------------------
// Weight transpose + cast: W fp32 (1024x1024, row-major K,N) -> WT bf16 (N,K)
// ---------------------------------------------------------------------------
struct TP { const float* s[6]; u16* d[6]; };

__global__ __launch_bounds__(256)
void transpose6(TP a) {
  __shared__ float tile[32][33];
  const float* S = a.s[blockIdx.z];
  u16* D = a.d[blockIdx.z];
  const int tx = threadIdx.x, ty = threadIdx.y;
  const int bx = blockIdx.x * 32, by = blockIdx.y * 32;
#pragma unroll
  for (int i = 0; i < 32; i += 8)
    tile[ty + i][tx] = S[(long)(by + ty + i) * 1024 + bx + tx];
  __syncthreads();
#pragma unroll
  for (int i = 0; i < 32; i += 8)
    D[(long)(bx + ty + i) * 1024 + by + tx] = f2bf(tile[tx][ty + i]);
}

// ---------------------------------------------------------------------------
// GEMM C = A * B  (m97 structure; unchanged from round 2 — it passed)
// ---------------------------------------------------------------------------
template <typename CT>
__global__ __launch_bounds__(256, 2)
void gemm_bt(const u16* __restrict__ A, const u16* __restrict__ Bt0,
             const u16* __restrict__ Bt1, CT* __restrict__ C0,
             CT* __restrict__ C1, const float* __restrict__ bias,
             int M, int RPB, int BSTR, int ROFF) {
  const u16* Bt = (blockIdx.z == 0) ? Bt0 : Bt1;
  CT* C = (blockIdx.z == 0) ? C0 : C1;
  __shared__ u16 As[128 * 32];
  __shared__ u16 Bs[128 * 32];
  const int t = threadIdx.x;
  const int w = t >> 6, lane = t & 63;
  const int m0 = blockIdx.x * 128, n0 = blockIdx.y * 128;
  const int subk = (lane & 3) * 8;

  long ag[2], bg[2];
  int lo[2];
#pragma unroll
  for (int r = 0; r < 2; ++r) {
    int m = m0 + r * 64 + w * 16 + (lane >> 2);
    if (m >= M) m = M - 1;  // clamp: duplicate loads, stores guarded below
    long row = (long)(m / RPB) * BSTR + (m % RPB) + ROFF;
    ag[r] = row * 1024 + subk;
    lo[r] = r * 2048 + w * 512 + (lane >> 2) * 32 + subk;
    int n = n0 + r * 64 + w * 16 + (lane >> 2);
    bg[r] = (long)n * 1024 + subk;
  }
  const int wm = w >> 1, wn = w & 1;
  const int lr = lane & 15, quad = lane >> 4;
  const u16* Ap = As + (wm * 64 + lr) * 32 + quad * 8;
  const u16* Bp = Bs + (wn * 64 + lr) * 32 + quad * 8;

  const f32x4 fz = {0.f, 0.f, 0.f, 0.f};
  f32x4 acc[4][4];
#pragma unroll
  for (int i = 0; i < 4; ++i)
#pragma unroll
    for (int j = 0; j < 4; ++j) acc[i][j] = fz;

  for (int k0 = 0; k0 < 1024; k0 += 32) {
    __syncthreads();
    async_cp16(A + ag[0] + k0, As + lo[0]);
    async_cp16(A + ag[1] + k0, As + lo[1]);
    async_cp16(Bt + bg[0] + k0, Bs + lo[0]);
    async_cp16(Bt + bg[1] + k0, Bs + lo[1]);
    __syncthreads();
    short8 a[4], b[4];
#pragma unroll
    for (int i = 0; i < 4; ++i) a[i] = *(const short8*)(Ap + i * 512);
#pragma unroll
    for (int i = 0; i < 4; ++i) b[i] = *(const short8*)(Bp + i * 512);
#pragma unroll
    for (int i = 0; i < 4; ++i)
#pragma unroll
      for (int j = 0; j < 4; ++j) acc[i][j] = mfma16(a[i], b[j], acc[i][j]);
  }

#pragma unroll
  for (int i = 0; i < 4; ++i) {
#pragma unroll
    for (int r = 0; r < 4; ++r) {
      int m = m0 + wm * 64 + i * 16 + quad * 4 + r;
      if (m < M) {
        long crow = ((long)(m / RPB) * BSTR + (m % RPB) + ROFF) * 1024;
#pragma unroll
        for (int j = 0; j < 4; ++j) {
          int n = n0 + wn * 64 + j * 16 + lr;
          float v = acc[i][j][r];
          if (bias) v += bias[n];
          if constexpr (std::is_same<CT, float>::value)
            C[crow + n] = v;
          else
            C[crow + n] = f2bf(v);
        }
      }
    }
  }
}

// ---------------------------------------------------------------------------
// Attention v2: one WG = (b, h, 4 q-tiles of 64 rows). V^T for BOTH phases
// staged ONCE per WG (txt at cols 0..76, img at cols 96..351), conflict-free
// (staging stores span 64 consecutive u16 per instruction). Scores stay in
// registers; P enters PV via a small 64x40 LDS chunk (32 cols at a time,
// wave-private rows -> no barriers) with XOR col-block swizzle:
//   store at col_blk ^ ((row>>2)&3)  -> writes hit all 32 banks 2-way (free),
//   b128 reads uniform 8/bank (the 1KB/instr floor).
// ---------------------------------------------------------------------------
constexpr int VSTR = 360;  // u16; 720 B row stride (16B-aligned, bank-spread)
constexpr int PSTR = 40;   // u16; 80 B row stride (16B-aligned)

template <int L, int JT, int COL0, int KOFF>
__device__ __forceinline__ void attn_phase2(const u16* __restrict__ kbh,
                                            const u16* __restrict__ Vt,
                                            u16* __restrict__ Pb, short8 aq0,
                                            short8 aq1, f32x4* oacc, int w,
                                            int lr, int quad) {
  f32x4 sacc[JT];
#pragma unroll
  for (int jt = 0; jt < JT; ++jt) {
    int kr = jt * 16 + lr;
    if (kr >= L) kr = L - 1;  // clamped dup loads; masked in softmax
    const u16* kp = kbh + (long)(KOFF + kr) * 1024;
    short8 b0 = *(const short8*)(kp + quad * 8);
    short8 b1 = *(const short8*)(kp + 32 + quad * 8);
    f32x4 z = {0.f, 0.f, 0.f, 0.f};
    z = mfma16(aq0, b0, z);
    sacc[jt] = mfma16(aq1, b1, z);
  }
  // softmax: lane (lr,quad) holds S[m=quad*4+r][n=jt*16+lr]
  float is[4];
#pragma unroll
  for (int r = 0; r < 4; ++r) {
    float mx = -3.0e38f;
#pragma unroll
    for (int jt = 0; jt < JT; ++jt) {
      int j = jt * 16 + lr;
      float v = (j < L) ? sacc[jt][r] * 0.125f : -3.0e38f;  // SCALE = 1/8
      sacc[jt][r] = v;
      mx = fmaxf(mx, v);
    }
#pragma unroll
    for (int d = 1; d < 16; d <<= 1) mx = fmaxf(mx, __shfl_xor(mx, d, 64));
    float s = 0.f;
#pragma unroll
    for (int jt = 0; jt < JT; ++jt) {
      float p = __expf(sacc[jt][r] - mx);
      sacc[jt][r] = p;
      s += p;
    }
#pragma unroll
    for (int d = 1; d < 16; d <<= 1) s += __shfl_xor(s, d, 64);
    is[r] = 1.0f / s;
  }
  // PV in 32-col chunks through swizzled LDS (wave-private rows, no barrier)
  const int rowblk = (lr >> 2) & 3;  // read-side (row>>2)&3 for row=w*16+lr
#pragma unroll
  for (int c = 0; c < JT / 2; ++c) {
#pragma unroll
    for (int half = 0; half < 2; ++half) {
      int cb = half * 2 + (lr >> 3);  // col block within chunk, 0..3
      int cbs = cb ^ quad;            // write-side (row>>2)&3 == quad
#pragma unroll
      for (int r = 0; r < 4; ++r) {
        int row = w * 16 + quad * 4 + r;
        Pb[row * PSTR + cbs * 8 + (lr & 7)] =
            f2bf(sacc[c * 2 + half][r] * is[r]);
      }
    }
    short8 pf =
        *(const short8*)(Pb + (w * 16 + lr) * PSTR + (quad ^ rowblk) * 8);
#pragma unroll
    for (int nt = 0; nt < 4; ++nt) {
      short8 vf = *(const short8*)(Vt + (nt * 16 + lr) * VSTR + COL0 + c * 32 +
                                   quad * 8);
      oacc[nt] = mfma16(pf, vf, oacc[nt]);
    }
  }
}

__global__ __launch_bounds__(256, 2)
void attn_kernel2(u16* __restrict__ q, const u16* __restrict__ kall,
                  const u16* __restrict__ vall) {
  __shared__ u16 Vt[64 * VSTR];  // 45 KB: V^T, d-major, both phases
  __shared__ u16 Pb[64 * PSTR];  // 5 KB: P chunk buffer
  const int t = threadIdx.x;
  const int w = t >> 6, lane = t & 63;
  const int lr = lane & 15, quad = lane >> 4;
  const int gq = blockIdx.x, h = blockIdx.y, b = blockIdx.z;
  const u16* kbh = kall + (long)b * 333 * 1024 + h * 64;
  const u16* vbh = vall + (long)b * 333 * 1024 + h * 64;

  // ---- stage V^T once: Vt[d][j], txt j=0..76 (77..95 zero), img j=96..351
  {
    const int j = t & 63, dgrp = t >> 6;  // dgrp == wave -> uniform per wave
#pragma unroll
    for (int jb = 0; jb < 384; jb += 64) {
      int jj = jb + j;
      if (jj < 352) {
        bool valid;
        long src;
        if (jj < 96) { valid = (jj < 77); src = jj; }
        else         { valid = true;      src = jj - 19; }  // 77 + (jj-96)
#pragma unroll
        for (int p = 0; p < 2; ++p) {
          int dg = dgrp + p * 4;  // 0..7
          short8 v = {0, 0, 0, 0, 0, 0, 0, 0};
          if (valid) v = *(const short8*)(vbh + src * 1024 + dg * 8);
#pragma unroll
          for (int e = 0; e < 8; ++e)
            Vt[(dg * 8 + e) * VSTR + jj] = (u16)v[e];  // 64 consec u16/instr
        }
      }
    }
  }
  __syncthreads();

  for (int qt = 0; qt < 4; ++qt) {
    const long row0 = (long)b * 2048 + gq * 256 + qt * 64;
    const long qoff = (row0 + w * 16 + lr) * 1024 + h * 64;
    short8 aq0 = *(const short8*)(q + qoff + quad * 8);
    short8 aq1 = *(const short8*)(q + qoff + 32 + quad * 8);
    const f32x4 fz = {0.f, 0.f, 0.f, 0.f};
    f32x4 oacc[4];
#pragma unroll
    for (int i = 0; i < 4; ++i) oacc[i] = fz;
    attn_phase2<77, 6, 0, 0>(kbh, Vt, Pb, aq0, aq1, oacc, w, lr, quad);
    attn_phase2<256, 16, 96, 77>(kbh, Vt, Pb, aq0, aq1, oacc, w, lr, quad);
    // write attention output over q in place (exclusive rows x h-cols)
#pragma unroll
    for (int nt = 0; nt < 4; ++nt)
#pragma unroll
      for (int r = 0; r < 4; ++r)
        q[(row0 + w * 16 + quad * 4 + r) * 1024 + h * 64 + nt * 16 + lr] =
            f2bf(oacc[nt][r]);
  }
}

// ---------------------------------------------------------------------------
extern "C" void kernel_launch(void* const* d_in, const int* in_sizes, int n_in,
                              void* d_out, int out_size, void* d_ws,
                              size_t ws_size, hipStream_t stream) {
  const float* x = (const float*)d_in[0];    // (16, 2048, 1024) fp32
  const float* ctx = (const float*)d_in[1];  // (16, 333, 1024) fp32
  u16* ws = (u16*)d_ws;
  u16* WT[6];
  for (int i = 0; i < 6; ++i) WT[i] = ws + (size_t)i * (1u << 20);
  u16* xb = ws + (size_t)6 * (1u << 20);
  u16* qb = xb + (size_t)(1u << 25);
  u16* ctxb = qb + (size_t)(1u << 25);
  u16* kall = ctxb + (size_t)16 * 333 * 1024;
  u16* vall = kall + (size_t)16 * 333 * 1024;
  float* out = (float*)d_out;

  cvt_f32_bf16<<<dim3(32768), dim3(256), 0, stream>>>(x, xb, 8388608);
  cvt_f32_bf16<<<dim3(5328), dim3(256), 0, stream>>>(ctx, ctxb, 1363968);

  TP tp;
  tp.s[0] = (const float*)d_in[2]; tp.d[0] = WT[0];  // Wq
  tp.s[1] = (const float*)d_in[3]; tp.d[1] = WT[1];  // Wk
  tp.s[2] = (const float*)d_in[4]; tp.d[2] = WT[2];  // Wv
  tp.s[3] = (const float*)d_in[5]; tp.d[3] = WT[3];  // Wk_ip
  tp.s[4] = (const float*)d_in[6]; tp.d[4] = WT[4];  // Wv_ip
  tp.s[5] = (const float*)d_in[7]; tp.d[5] = WT[5];  // Wo
  transpose6<<<dim3(32, 32, 6), dim3(32, 8, 1), 0, stream>>>(tp);

  gemm_bt<u16><<<dim3(256, 8, 1), dim3(256), 0, stream>>>(
      xb, WT[0], WT[0], qb, qb, (const float*)nullptr, 32768, 2048, 2048, 0);
  gemm_bt<u16><<<dim3(10, 8, 2), dim3(256), 0, stream>>>(
      ctxb, WT[1], WT[2], kall, vall, (const float*)nullptr, 1232, 77, 333, 0);
  gemm_bt<u16><<<dim3(32, 8, 2), dim3(256), 0, stream>>>(
      ctxb, WT[3], WT[4], kall, vall, (const float*)nullptr, 4096, 256, 333, 77);
  attn_kernel2<<<dim3(8, 16, 16), dim3(256), 0, stream>>>(qb, kall, vall);
  gemm_bt<float><<<dim3(256, 8, 1), dim3(256), 0, stream>>>(
      qb, WT[5], WT[5], out, out, (const float*)d_in[8], 32768, 2048, 2048, 0);
}